// Round 1
// baseline (2744.667 us; speedup 1.0000x reference)
//
#include <hip/hip_runtime.h>
#include <math.h>

#define S_TOTAL 4096
#define M_TOTAL 16384   // B * S

// ---------------- gather + diff: out[(b*S+s)*C + c] = feat[b][c][cid[s]] - feat[b][c][nid[s]]
__global__ __launch_bounds__(64) void gather_diff_kernel(
    const float* __restrict__ feat, const int* __restrict__ cid,
    const int* __restrict__ nid, float* __restrict__ out, int C, int HW)
{
    int s = blockIdx.x;
    int b = blockIdx.y;
    int ci = cid[s], ni = nid[s];
    const float* fb = feat + (size_t)b * C * HW;
    float* o = out + ((size_t)b * S_TOTAL + s) * C;
    for (int c = threadIdx.x; c < C; c += 64) {
        o[c] = fb[(size_t)c * HW + ci] - fb[(size_t)c * HW + ni];
    }
}

// ---------------- fp32 GEMM: Y[M,N] = act(X[M,K] @ W[N,K]^T + bias)
// 128x128 block tile, BK=16, 256 threads, 8x8 per thread.
// LDS layouts transposed ([k][m], [k][n]) so fragments are float4 reads.
// Fragment cols/rows split {t*4 .. t*4+3} U {64+t*4 ..} for conflict-free b128.
#define BM 128
#define BN 128
#define BK 16
#define LDT 132   // BM + 4 pad

__global__ __launch_bounds__(256) void gemm_kernel(
    const float* __restrict__ X,   // [M,K] row-major (M = grid.y*128)
    const float* __restrict__ W,   // [N,K] row-major
    const float* __restrict__ bias,// [N]
    float* __restrict__ Y,         // [M,N]
    int N, int K, int relu)
{
    __shared__ float As[BK][LDT];
    __shared__ float Bs[BK][LDT];
    const int tid = threadIdx.x;
    const int tx = tid & 15, ty = tid >> 4;
    const int m0 = blockIdx.y * BM;
    const int n0 = blockIdx.x * BN;

    float acc[8][8];
#pragma unroll
    for (int i = 0; i < 8; ++i)
#pragma unroll
        for (int j = 0; j < 8; ++j) acc[i][j] = 0.f;

    for (int k0 = 0; k0 < K; k0 += BK) {
        // stage X tile (128 rows x 16 k), transpose into As[k][m]
#pragma unroll
        for (int t = tid; t < BM * BK / 4; t += 256) {
            int row = t >> 2;
            int kq = (t & 3) << 2;
            const float4 v = *(const float4*)(X + (size_t)(m0 + row) * K + k0 + kq);
            As[kq + 0][row] = v.x; As[kq + 1][row] = v.y;
            As[kq + 2][row] = v.z; As[kq + 3][row] = v.w;
        }
        // stage W tile (128 cols x 16 k), transpose into Bs[k][n]
#pragma unroll
        for (int t = tid; t < BN * BK / 4; t += 256) {
            int col = t >> 2;
            int kq = (t & 3) << 2;
            float4 v = make_float4(0.f, 0.f, 0.f, 0.f);
            if (n0 + col < N)
                v = *(const float4*)(W + (size_t)(n0 + col) * K + k0 + kq);
            Bs[kq + 0][col] = v.x; Bs[kq + 1][col] = v.y;
            Bs[kq + 2][col] = v.z; Bs[kq + 3][col] = v.w;
        }
        __syncthreads();
#pragma unroll
        for (int kk = 0; kk < BK; ++kk) {
            float4 a0 = *(const float4*)&As[kk][ty * 4];
            float4 a1 = *(const float4*)&As[kk][64 + ty * 4];
            float4 b0 = *(const float4*)&Bs[kk][tx * 4];
            float4 b1 = *(const float4*)&Bs[kk][64 + tx * 4];
            float ar[8] = {a0.x, a0.y, a0.z, a0.w, a1.x, a1.y, a1.z, a1.w};
            float br[8] = {b0.x, b0.y, b0.z, b0.w, b1.x, b1.y, b1.z, b1.w};
#pragma unroll
            for (int i = 0; i < 8; ++i)
#pragma unroll
                for (int j = 0; j < 8; ++j)
                    acc[i][j] = fmaf(ar[i], br[j], acc[i][j]);
        }
        __syncthreads();
    }

#pragma unroll
    for (int i = 0; i < 8; ++i) {
        int row = m0 + ((i < 4) ? (ty * 4 + i) : (64 + ty * 4 + i - 4));
#pragma unroll
        for (int j = 0; j < 8; ++j) {
            int col = n0 + ((j < 4) ? (tx * 4 + j) : (64 + tx * 4 + j - 4));
            if (col < N) {
                float v = acc[i][j] + bias[col];
                if (relu) v = fmaxf(v, 0.f);
                Y[(size_t)row * N + col] = v;
            }
        }
    }
}

// ---------------- fused NCE: per (b, 64-row tile), online LSE over all t plus pos.
// Fq/Fk: [B, S, Cout]. Q tile pre-scaled by 1/tau. Per-thread (m,l) over its
// column slice {tx + 16j}; butterfly-combine across the 16 tx lanes at the end.
__global__ __launch_bounds__(256) void nce_kernel(
    const float* __restrict__ Fq, const float* __restrict__ Fk,
    float* __restrict__ out, int Cout, int stride, float inv_tau)
{
    extern __shared__ float sm[];
    float* Qs = sm;                    // [64][stride]
    float* Ks = sm + 64 * stride;      // [64][stride]
    __shared__ float red[16];

    const int tid = threadIdx.x;
    const int tx = tid & 15, ty = tid >> 4;
    const int b = blockIdx.y;
    const int r0 = blockIdx.x * 64;
    const int c4 = Cout >> 2;

    // load + scale Q tile
    const float* fqb = Fq + ((size_t)b * S_TOTAL + r0) * Cout;
    for (int t = tid; t < 64 * c4; t += 256) {
        int r = t / c4;
        int c = (t % c4) << 2;
        float4 v = *(const float4*)(fqb + (size_t)r * Cout + c);
        v.x *= inv_tau; v.y *= inv_tau; v.z *= inv_tau; v.w *= inv_tau;
        *(float4*)&Qs[r * stride + c] = v;
    }

    float m[4], l[4];
#pragma unroll
    for (int i = 0; i < 4; ++i) { m[i] = -1e30f; l[i] = 0.f; }

    for (int t0 = 0; t0 < S_TOTAL; t0 += 64) {
        __syncthreads();
        const float* fkb = Fk + ((size_t)b * S_TOTAL + t0) * Cout;
        for (int t = tid; t < 64 * c4; t += 256) {
            int r = t / c4;
            int c = (t % c4) << 2;
            *(float4*)&Ks[r * stride + c] = *(const float4*)(fkb + (size_t)r * Cout + c);
        }
        __syncthreads();

        float d[4][4];
#pragma unroll
        for (int i = 0; i < 4; ++i)
#pragma unroll
            for (int j = 0; j < 4; ++j) d[i][j] = 0.f;

        for (int c = 0; c < Cout; c += 4) {
            float4 q[4], k[4];
#pragma unroll
            for (int i = 0; i < 4; ++i)
                q[i] = *(const float4*)&Qs[(ty + 16 * i) * stride + c];
#pragma unroll
            for (int j = 0; j < 4; ++j)
                k[j] = *(const float4*)&Ks[(tx + 16 * j) * stride + c];
#pragma unroll
            for (int i = 0; i < 4; ++i)
#pragma unroll
                for (int j = 0; j < 4; ++j) {
                    d[i][j] = fmaf(q[i].x, k[j].x, d[i][j]);
                    d[i][j] = fmaf(q[i].y, k[j].y, d[i][j]);
                    d[i][j] = fmaf(q[i].z, k[j].z, d[i][j]);
                    d[i][j] = fmaf(q[i].w, k[j].w, d[i][j]);
                }
        }
#pragma unroll
        for (int i = 0; i < 4; ++i) {
            float mx = fmaxf(fmaxf(d[i][0], d[i][1]), fmaxf(d[i][2], d[i][3]));
            float mn = fmaxf(m[i], mx);
            l[i] = l[i] * __expf(m[i] - mn)
                 + __expf(d[i][0] - mn) + __expf(d[i][1] - mn)
                 + __expf(d[i][2] - mn) + __expf(d[i][3] - mn);
            m[i] = mn;
        }
    }

    // combine (m,l) across the 16 tx lanes (lane bits 0..3)
#pragma unroll
    for (int off = 1; off < 16; off <<= 1) {
#pragma unroll
        for (int i = 0; i < 4; ++i) {
            float mo = __shfl_xor(m[i], off);
            float lo = __shfl_xor(l[i], off);
            float mn = fmaxf(m[i], mo);
            l[i] = l[i] * __expf(m[i] - mn) + lo * __expf(mo - mn);
            m[i] = mn;
        }
    }

    // pos (diag) + per-row loss; Qs is already scaled by 1/tau
    float lsum = 0.f;
#pragma unroll
    for (int i = 0; i < 4; ++i) {
        int r = ty + 16 * i;
        const float* kp = Fk + ((size_t)b * S_TOTAL + r0 + r) * Cout;
        float p = 0.f;
        for (int c = tx * 4; c < Cout; c += 64) {
            float4 q = *(const float4*)&Qs[r * stride + c];
            p += q.x * kp[c] + q.y * kp[c + 1] + q.z * kp[c + 2] + q.w * kp[c + 3];
        }
#pragma unroll
        for (int off = 1; off < 16; off <<= 1) p += __shfl_xor(p, off);
        lsum += (m[i] + __logf(l[i]) - p);
    }

    if (tx == 0) red[ty] = lsum;
    __syncthreads();
    if (tid == 0) {
        float s = 0.f;
        for (int k2 = 0; k2 < 16; ++k2) s += red[k2];
        atomicAdd(out, s * (1.0f / (float)M_TOTAL));
    }
}

// ---------------- orchestration
extern "C" void kernel_launch(void* const* d_in, const int* in_sizes, int n_in,
                              void* d_out, int out_size, void* d_ws, size_t ws_size,
                              hipStream_t stream)
{
    (void)in_sizes; (void)n_in; (void)out_size;
    hipMemsetAsync(d_out, 0, sizeof(float), stream);

    static const int Cs[4]  = {64, 128, 256, 512};
    static const int HWs[4] = {256 * 256, 128 * 128, 64 * 64, 32 * 32};

    // workspace carve (floats): bufA 8M, bufB 8M, Fq 2M, Fk 2M  => 80 MB
    float* bufA = (float*)d_ws;
    float* bufB = bufA + (size_t)M_TOTAL * 512;
    float* Fq   = bufB + (size_t)M_TOTAL * 512;
    float* Fk   = Fq   + (size_t)M_TOTAL * 128;

    for (int i = 0; i < 4; ++i) {
        const int C = Cs[i], HW = HWs[i], Cout = C / 4;
        const float* fq  = (const float*)d_in[i * 10 + 0];
        const float* fk  = (const float*)d_in[i * 10 + 1];
        const int*   cid = (const int*)  d_in[i * 10 + 2];
        const int*   nid = (const int*)  d_in[i * 10 + 3];
        const float* w0  = (const float*)d_in[i * 10 + 4];
        const float* b0  = (const float*)d_in[i * 10 + 5];
        const float* w1  = (const float*)d_in[i * 10 + 6];
        const float* b1  = (const float*)d_in[i * 10 + 7];
        const float* w2  = (const float*)d_in[i * 10 + 8];
        const float* b2  = (const float*)d_in[i * 10 + 9];

        for (int qk = 0; qk < 2; ++qk) {
            const float* feat = qk ? fk : fq;
            float* F = qk ? Fk : Fq;
            gather_diff_kernel<<<dim3(S_TOTAL, 4), 64, 0, stream>>>(
                feat, cid, nid, bufA, C, HW);
            gemm_kernel<<<dim3((C + BN - 1) / BN, M_TOTAL / BM), 256, 0, stream>>>(
                bufA, w0, b0, bufB, C, C, 1);
            gemm_kernel<<<dim3((C + BN - 1) / BN, M_TOTAL / BM), 256, 0, stream>>>(
                bufB, w1, b1, bufA, C, C, 1);
            gemm_kernel<<<dim3((Cout + BN - 1) / BN, M_TOTAL / BM), 256, 0, stream>>>(
                bufA, w2, b2, F, Cout, C, 0);
        }

        const int stride = (Cout == 16) ? 36 : (Cout + 4);  // % 32 == 4 -> 2-way (free)
        const size_t shmem = (size_t)2 * 64 * stride * sizeof(float);
        nce_kernel<<<dim3(S_TOTAL / 64, 4), 256, shmem, stream>>>(
            Fq, Fk, (float*)d_out, Cout, stride, 100.0f /* 1/tau */);
    }
}

// Round 2
// 1866.235 us; speedup vs baseline: 1.4707x; 1.4707x over previous
//
#include <hip/hip_runtime.h>
#include <math.h>

#define S_TOTAL 4096
#define M_TOTAL 16384   // B * S
#define BK 16
#define NSLICE 8        // t-dimension slices for NCE parallelism

// ---------------- gather + diff: out[(b*S+s)*C + c] = feat[b][c][cid[s]] - feat[b][c][nid[s]]
__global__ __launch_bounds__(64) void gather_diff_kernel(
    const float* __restrict__ feat, const int* __restrict__ cid,
    const int* __restrict__ nid, float* __restrict__ out, int C, int HW)
{
    int s = blockIdx.x;
    int b = blockIdx.y;
    int ci = cid[s], ni = nid[s];
    const float* fb = feat + (size_t)b * C * HW;
    float* o = out + ((size_t)b * S_TOTAL + s) * C;
    for (int c = threadIdx.x; c < C; c += 64) {
        o[c] = fb[(size_t)c * HW + ci] - fb[(size_t)c * HW + ni];
    }
}

// ---------------- fragment index maps (row: ty, col: tx of a 16x16 thread grid)
template<int TM_>
__device__ __forceinline__ int rmap(int ty, int i) {
    if constexpr (TM_ == 8) return (i < 4) ? (ty * 4 + i) : (64 + ty * 4 + i - 4);
    else                    return ty * 4 + i;            // TM_ == 4
}
template<int TN_>
__device__ __forceinline__ int cmap(int tx, int j) {
    if constexpr (TN_ == 8)      return (j < 4) ? (tx * 4 + j) : (64 + tx * 4 + j - 4);
    else if constexpr (TN_ == 4) return tx * 4 + j;
    else if constexpr (TN_ == 2) return tx * 2 + j;
    else                         return tx;               // TN_ == 1
}
template<int TW>
__device__ __forceinline__ void load_frag(const float* base, int t, float* r) {
    if constexpr (TW == 8) {
        float4 v0 = *(const float4*)(base + t * 4);
        float4 v1 = *(const float4*)(base + 64 + t * 4);
        r[0] = v0.x; r[1] = v0.y; r[2] = v0.z; r[3] = v0.w;
        r[4] = v1.x; r[5] = v1.y; r[6] = v1.z; r[7] = v1.w;
    } else if constexpr (TW == 4) {
        float4 v0 = *(const float4*)(base + t * 4);
        r[0] = v0.x; r[1] = v0.y; r[2] = v0.z; r[3] = v0.w;
    } else if constexpr (TW == 2) {
        float2 v0 = *(const float2*)(base + t * 2);
        r[0] = v0.x; r[1] = v0.y;
    } else {
        r[0] = base[t];
    }
}

// ---------------- fp32 GEMM: Y[M,N] = act(X[M,K] @ W[N,K]^T + bias)
// BMxBN block tile, BK=16, 256 threads, TMxTN per thread.
// LDS transposed ([k][m], [k][n]); frag cols split for conflict-free b128.
template<int BM_, int TM_, int BN_, int TN_>
__global__ __launch_bounds__(256) void gemm_t(
    const float* __restrict__ X,   // [M,K] row-major
    const float* __restrict__ W,   // [N,K] row-major
    const float* __restrict__ bias,// [N]
    float* __restrict__ Y,         // [M,N]
    int N, int K, int relu)
{
    __shared__ float As[BK][BM_ + 4];
    __shared__ float Bs[BK][BN_ + 4];
    const int tid = threadIdx.x;
    const int tx = tid & 15, ty = tid >> 4;
    const int m0 = blockIdx.y * BM_;
    const int n0 = blockIdx.x * BN_;

    float acc[TM_][TN_];
#pragma unroll
    for (int i = 0; i < TM_; ++i)
#pragma unroll
        for (int j = 0; j < TN_; ++j) acc[i][j] = 0.f;

    for (int k0 = 0; k0 < K; k0 += BK) {
#pragma unroll
        for (int t = tid; t < BM_ * 4; t += 256) {
            int row = t >> 2, kq = (t & 3) << 2;
            float4 v = *(const float4*)(X + (size_t)(m0 + row) * K + k0 + kq);
            As[kq + 0][row] = v.x; As[kq + 1][row] = v.y;
            As[kq + 2][row] = v.z; As[kq + 3][row] = v.w;
        }
        for (int t = tid; t < BN_ * 4; t += 256) {
            int col = t >> 2, kq = (t & 3) << 2;
            float4 v = *(const float4*)(W + (size_t)(n0 + col) * K + k0 + kq);
            Bs[kq + 0][col] = v.x; Bs[kq + 1][col] = v.y;
            Bs[kq + 2][col] = v.z; Bs[kq + 3][col] = v.w;
        }
        __syncthreads();
#pragma unroll
        for (int kk = 0; kk < BK; ++kk) {
            float ar[TM_], br[TN_];
            load_frag<TM_>(&As[kk][0], ty, ar);
            load_frag<TN_>(&Bs[kk][0], tx, br);
#pragma unroll
            for (int i = 0; i < TM_; ++i)
#pragma unroll
                for (int j = 0; j < TN_; ++j)
                    acc[i][j] = fmaf(ar[i], br[j], acc[i][j]);
        }
        __syncthreads();
    }

#pragma unroll
    for (int i = 0; i < TM_; ++i) {
        int row = m0 + rmap<TM_>(ty, i);
#pragma unroll
        for (int j = 0; j < TN_; ++j) {
            int col = n0 + cmap<TN_>(tx, j);
            float v = acc[i][j] + bias[col];
            if (relu) v = fmaxf(v, 0.f);
            Y[(size_t)row * N + col] = v;
        }
    }
}

// ---------------- NCE partial: flash-style online LSE over a t-slice.
// 128-row x 128-col tiles, 8x8 per thread (same fragment structure as gemm_t).
// Writes per-(row, slice) partial (m, l) to ws. Q scaled by inv_tau at staging.
__global__ __launch_bounds__(256) void nce_partial(
    const float* __restrict__ Fq, const float* __restrict__ Fk,
    float2* __restrict__ partial, int Cout, float inv_tau)
{
    __shared__ float As[BK][132];
    __shared__ float Bs[BK][132];
    const int tid = threadIdx.x;
    const int tx = tid & 15, ty = tid >> 4;
    const int b = blockIdx.z;
    const int slice = blockIdx.y;
    const int r0 = blockIdx.x * 128;
    const float* Q  = Fq + (size_t)b * S_TOTAL * Cout;
    const float* Kp = Fk + (size_t)b * S_TOTAL * Cout;

    float m[8], l[8];
#pragma unroll
    for (int i = 0; i < 8; ++i) { m[i] = -1e30f; l[i] = 0.f; }

    const int t_begin = slice * (S_TOTAL / NSLICE);
    const int t_end   = t_begin + (S_TOTAL / NSLICE);
    for (int t0 = t_begin; t0 < t_end; t0 += 128) {
        float d[8][8];
#pragma unroll
        for (int i = 0; i < 8; ++i)
#pragma unroll
            for (int j = 0; j < 8; ++j) d[i][j] = 0.f;

        for (int k0 = 0; k0 < Cout; k0 += BK) {
#pragma unroll
            for (int t = tid; t < 128 * 4; t += 256) {
                int row = t >> 2, kq = (t & 3) << 2;
                float4 v = *(const float4*)(Q + (size_t)(r0 + row) * Cout + k0 + kq);
                As[kq + 0][row] = v.x * inv_tau; As[kq + 1][row] = v.y * inv_tau;
                As[kq + 2][row] = v.z * inv_tau; As[kq + 3][row] = v.w * inv_tau;
            }
#pragma unroll
            for (int t = tid; t < 128 * 4; t += 256) {
                int col = t >> 2, kq = (t & 3) << 2;
                float4 v = *(const float4*)(Kp + (size_t)(t0 + col) * Cout + k0 + kq);
                Bs[kq + 0][col] = v.x; Bs[kq + 1][col] = v.y;
                Bs[kq + 2][col] = v.z; Bs[kq + 3][col] = v.w;
            }
            __syncthreads();
#pragma unroll
            for (int kk = 0; kk < BK; ++kk) {
                float ar[8], br[8];
                load_frag<8>(&As[kk][0], ty, ar);
                load_frag<8>(&Bs[kk][0], tx, br);
#pragma unroll
                for (int i = 0; i < 8; ++i)
#pragma unroll
                    for (int j = 0; j < 8; ++j)
                        d[i][j] = fmaf(ar[i], br[j], d[i][j]);
            }
            __syncthreads();
        }

        // online-softmax update
#pragma unroll
        for (int i = 0; i < 8; ++i) {
            float mx = d[i][0];
#pragma unroll
            for (int j = 1; j < 8; ++j) mx = fmaxf(mx, d[i][j]);
            float mn = fmaxf(m[i], mx);
            float s = l[i] * __expf(m[i] - mn);
#pragma unroll
            for (int j = 0; j < 8; ++j) s += __expf(d[i][j] - mn);
            l[i] = s;
            m[i] = mn;
        }
    }

    // combine (m,l) across the 16 tx lanes (same rows, different cols)
#pragma unroll
    for (int off = 1; off < 16; off <<= 1) {
#pragma unroll
        for (int i = 0; i < 8; ++i) {
            float mo = __shfl_xor(m[i], off);
            float lo = __shfl_xor(l[i], off);
            float mn = fmaxf(m[i], mo);
            l[i] = l[i] * __expf(m[i] - mn) + lo * __expf(mo - mn);
            m[i] = mn;
        }
    }
    if (tx == 0) {
#pragma unroll
        for (int i = 0; i < 8; ++i) {
            int row = r0 + rmap<8>(ty, i);
            partial[(size_t)(b * NSLICE + slice) * S_TOTAL + row] = make_float2(m[i], l[i]);
        }
    }
}

// ---------------- NCE reduce: merge slice partials + pos diagonal -> loss sum.
__global__ __launch_bounds__(256) void nce_reduce(
    const float* __restrict__ Fq, const float* __restrict__ Fk,
    const float2* __restrict__ partial, float* __restrict__ out,
    int Cout, float inv_tau)
{
    __shared__ float red[4];
    const int tid = threadIdx.x;
    const int g = blockIdx.x * 256 + tid;   // 0 .. 16383
    const int b = g >> 12, s = g & 4095;

    float M = -1e30f, L = 0.f;
    for (int sl = 0; sl < NSLICE; ++sl) {
        float2 p = partial[(size_t)(b * NSLICE + sl) * S_TOTAL + s];
        float mn = fmaxf(M, p.x);
        L = L * __expf(M - mn) + p.y * __expf(p.x - mn);
        M = mn;
    }
    const float* q = Fq + (size_t)g * Cout;
    const float* k = Fk + (size_t)g * Cout;
    float pos = 0.f;
    for (int c = 0; c < Cout; c += 4) {
        float4 a  = *(const float4*)(q + c);
        float4 bb = *(const float4*)(k + c);
        pos += a.x * bb.x + a.y * bb.y + a.z * bb.z + a.w * bb.w;
    }
    float v = M + __logf(L) - pos * inv_tau;
#pragma unroll
    for (int off = 1; off < 64; off <<= 1) v += __shfl_xor(v, off);
    if ((tid & 63) == 0) red[tid >> 6] = v;
    __syncthreads();
    if (tid == 0) {
        float sum = red[0] + red[1] + red[2] + red[3];
        atomicAdd(out, sum * (1.0f / (float)M_TOTAL));
    }
}

// ---------------- host-side GEMM dispatch (N always divides chosen BN)
static void launch_gemm(const float* X, const float* W, const float* bias, float* Y,
                        int N, int K, int relu, hipStream_t stream)
{
    if (N >= 256)
        gemm_t<128, 8, 128, 8><<<dim3(N / 128, M_TOTAL / 128), 256, 0, stream>>>(X, W, bias, Y, N, K, relu);
    else if (N == 128)
        gemm_t<64, 4, 128, 8><<<dim3(1, M_TOTAL / 64), 256, 0, stream>>>(X, W, bias, Y, N, K, relu);
    else if (N == 64)
        gemm_t<64, 4, 64, 4><<<dim3(1, M_TOTAL / 64), 256, 0, stream>>>(X, W, bias, Y, N, K, relu);
    else if (N == 32)
        gemm_t<64, 4, 32, 2><<<dim3(1, M_TOTAL / 64), 256, 0, stream>>>(X, W, bias, Y, N, K, relu);
    else
        gemm_t<64, 4, 16, 1><<<dim3(1, M_TOTAL / 64), 256, 0, stream>>>(X, W, bias, Y, N, K, relu);
}

// ---------------- orchestration
extern "C" void kernel_launch(void* const* d_in, const int* in_sizes, int n_in,
                              void* d_out, int out_size, void* d_ws, size_t ws_size,
                              hipStream_t stream)
{
    (void)in_sizes; (void)n_in; (void)out_size; (void)ws_size;
    hipMemsetAsync(d_out, 0, sizeof(float), stream);

    static const int Cs[4]  = {64, 128, 256, 512};
    static const int HWs[4] = {256 * 256, 128 * 128, 64 * 64, 32 * 32};

    // workspace carve (floats): bufA 8M, bufB 8M, Fq 2M, Fk 2M  => 80 MB
    float* bufA = (float*)d_ws;
    float* bufB = bufA + (size_t)M_TOTAL * 512;
    float* Fq   = bufB + (size_t)M_TOTAL * 512;
    float* Fk   = Fq   + (size_t)M_TOTAL * 128;
    float2* partial = (float2*)bufA;   // reused: gemms are done before nce_partial runs

    for (int i = 0; i < 4; ++i) {
        const int C = Cs[i], HW = HWs[i], Cout = C / 4;
        const float* fq  = (const float*)d_in[i * 10 + 0];
        const float* fk  = (const float*)d_in[i * 10 + 1];
        const int*   cid = (const int*)  d_in[i * 10 + 2];
        const int*   nid = (const int*)  d_in[i * 10 + 3];
        const float* w0  = (const float*)d_in[i * 10 + 4];
        const float* b0  = (const float*)d_in[i * 10 + 5];
        const float* w1  = (const float*)d_in[i * 10 + 6];
        const float* b1  = (const float*)d_in[i * 10 + 7];
        const float* w2  = (const float*)d_in[i * 10 + 8];
        const float* b2  = (const float*)d_in[i * 10 + 9];

        for (int qk = 0; qk < 2; ++qk) {
            const float* feat = qk ? fk : fq;
            float* F = qk ? Fk : Fq;
            gather_diff_kernel<<<dim3(S_TOTAL, 4), 64, 0, stream>>>(
                feat, cid, nid, bufB, C, HW);
            launch_gemm(bufB, w0, b0, bufA, C, C, 1, stream);
            launch_gemm(bufA, w1, b1, bufB, C, C, 1, stream);
            launch_gemm(bufB, w2, b2, F, Cout, C, 0, stream);
        }

        nce_partial<<<dim3(S_TOTAL / 128, NSLICE, 4), 256, 0, stream>>>(
            Fq, Fk, partial, Cout, 100.0f /* 1/tau */);
        nce_reduce<<<dim3(M_TOTAL / 256), 256, 0, stream>>>(
            Fq, Fk, partial, (float*)d_out, Cout, 100.0f);
    }
}

// Round 3
// 991.031 us; speedup vs baseline: 2.7695x; 1.8831x over previous
//
#include <hip/hip_runtime.h>
#include <hip/hip_bf16.h>
#include <math.h>

#define S_TOTAL 4096
#define B_TOTAL 4
#define M_TOTAL 16384
#define NSLICE 4

typedef __attribute__((ext_vector_type(8))) short bf16x8;
typedef __attribute__((ext_vector_type(4))) float f32x4;

__device__ __forceinline__ void glds16(const void* src, void* lds_base) {
    __builtin_amdgcn_global_load_lds(
        (const __attribute__((address_space(1))) void*)src,
        (__attribute__((address_space(3))) void*)lds_base, 16, 0, 0);
}

// ---------------- gather + diff -> bf16 [M, C]
__global__ __launch_bounds__(64) void gather_diff(
    const float* __restrict__ feat, const int* __restrict__ cid,
    const int* __restrict__ nid, __hip_bfloat16* __restrict__ out, int C, int HW)
{
    int s = blockIdx.x, bb = blockIdx.y;
    int ci = cid[s], ni = nid[s];
    const float* fb = feat + (size_t)bb * C * HW;
    __hip_bfloat16* o = out + ((size_t)bb * S_TOTAL + s) * C;
    for (int c = threadIdx.x; c < C; c += 64)
        o[c] = __float2bfloat16(fb[(size_t)c * HW + ci] - fb[(size_t)c * HW + ni]);
}

// ---------------- fp32 -> bf16 weight conversion (12 matrices, one kernel)
struct WArgs { const float* s[12]; __hip_bfloat16* d[12]; int n[12]; };
__global__ __launch_bounds__(256) void convert_w(WArgs a) {
    int mtx = blockIdx.y, n = a.n[mtx];
    const float* s = a.s[mtx];
    __hip_bfloat16* d = a.d[mtx];
    for (int i = blockIdx.x * 256 + threadIdx.x; i < n; i += gridDim.x * 256)
        d[i] = __float2bfloat16(s[i]);
}

// ---------------- bf16 MFMA GEMM: Y[M,N] = act(X[M,K] @ W[N,K]^T + bias)
// 128 x BN block tile, BK=32, 4 waves, 16x16x32 bf16 MFMA, glds width-16 staging.
template<int BN>
__global__ __launch_bounds__(256) void gemm_mfma(
    const __hip_bfloat16* __restrict__ X, const __hip_bfloat16* __restrict__ W,
    const float* __restrict__ bias, __hip_bfloat16* __restrict__ Y,
    int K, int ldY, int relu)
{
    constexpr int WN = (BN == 128) ? 2 : 1;
    constexpr int WM = 4 / WN;
    constexpr int RM = 128 / WM;   // rows per wave
    constexpr int RN = BN / WN;    // cols per wave
    constexpr int TMI = RM / 16, TNI = RN / 16;
    __shared__ __hip_bfloat16 As[128 * 32];
    __shared__ __hip_bfloat16 Bs[BN * 32];
    const int lane = threadIdx.x & 63, wave = threadIdx.x >> 6;
    const int quad = lane >> 4, l15 = lane & 15;
    const int wm = wave % WM, wn = wave / WM;
    const int m0 = blockIdx.y * 128, n0 = blockIdx.x * BN;

    f32x4 acc[TMI][TNI];
#pragma unroll
    for (int i = 0; i < TMI; ++i)
#pragma unroll
        for (int j = 0; j < TNI; ++j) acc[i][j] = (f32x4){0.f, 0.f, 0.f, 0.f};

    for (int k0 = 0; k0 < K; k0 += 32) {
        // stage A: 128x32 bf16 (512 granules of 16B), contiguous row-major
        for (int h = 0; h < 2; ++h) {
            int g0 = h * 256 + wave * 64;
            int g = g0 + lane;
            glds16(X + (size_t)(m0 + (g >> 2)) * K + k0 + (g & 3) * 8,
                   (char*)As + g0 * 16);
        }
        // stage B: BN x 32 bf16
        for (int g0 = wave * 64; g0 < BN * 4; g0 += 256) {
            int g = g0 + lane;
            glds16(W + (size_t)(n0 + (g >> 2)) * K + k0 + (g & 3) * 8,
                   (char*)Bs + g0 * 16);
        }
        __syncthreads();
        bf16x8 af[TMI], bfr[TNI];
#pragma unroll
        for (int i = 0; i < TMI; ++i)
            af[i] = *(const bf16x8*)(As + (wm * RM + i * 16 + l15) * 32 + quad * 8);
#pragma unroll
        for (int j = 0; j < TNI; ++j)
            bfr[j] = *(const bf16x8*)(Bs + (wn * RN + j * 16 + l15) * 32 + quad * 8);
#pragma unroll
        for (int i = 0; i < TMI; ++i)
#pragma unroll
            for (int j = 0; j < TNI; ++j)
                acc[i][j] = __builtin_amdgcn_mfma_f32_16x16x32_bf16(
                    af[i], bfr[j], acc[i][j], 0, 0, 0);
        __syncthreads();
    }

    // epilogue: bias + relu + bf16 store. C/D: col=lane&15, row=quad*4+reg.
#pragma unroll
    for (int j = 0; j < TNI; ++j) {
        int col = n0 + wn * RN + j * 16 + l15;
        float bv = bias[col];
#pragma unroll
        for (int i = 0; i < TMI; ++i) {
            int row = m0 + wm * RM + i * 16 + quad * 4;
#pragma unroll
            for (int r = 0; r < 4; ++r) {
                float v = acc[i][j][r] + bv;
                if (relu) v = fmaxf(v, 0.f);
                Y[(size_t)(row + r) * ldY + col] = __float2bfloat16(v);
            }
        }
    }
}

// ---------------- MFMA NCE: per (b, 128-row tile, t-slice) flash LSE (base-2).
// Q tile resident in LDS; K tiles streamed. Scores stay in MFMA C-layout;
// each lane owns 16 rows (mi*4+reg) x 4 cols (ni) per tile. Partials written
// per (slice, wn col-half): 8 parts merged in nce_reduce.
template<int KPAD>
__global__ __launch_bounds__(256) void nce_mfma(
    const __hip_bfloat16* __restrict__ Fq, const __hip_bfloat16* __restrict__ Fk,
    float2* __restrict__ partial, float s2)
{
    __shared__ __hip_bfloat16 Qs[128 * KPAD];
    __shared__ __hip_bfloat16 Ks[128 * KPAD];
    const int lane = threadIdx.x & 63, wave = threadIdx.x >> 6;
    const int quad = lane >> 4, l15 = lane & 15;
    const int wm = wave & 1, wn = wave >> 1;
    const int bb = blockIdx.z, slice = blockIdx.y, r0 = blockIdx.x * 128;
    constexpr int GR = KPAD / 8;       // 16B granules per row
    constexpr int GQ = 128 * GR;

    const __hip_bfloat16* Qb = Fq + ((size_t)bb * S_TOTAL + r0) * KPAD;
    for (int g0 = wave * 64; g0 < GQ; g0 += 256) {
        int g = g0 + lane;
        glds16(Qb + (size_t)(g / GR) * KPAD + (g % GR) * 8, (char*)Qs + g0 * 16);
    }

    float m[16], l[16];
#pragma unroll
    for (int i = 0; i < 16; ++i) { m[i] = -1e30f; l[i] = 0.f; }

    const int t_begin = slice * (S_TOTAL / NSLICE);
    for (int t0 = t_begin; t0 < t_begin + S_TOTAL / NSLICE; t0 += 128) {
        __syncthreads();   // Ks free to overwrite; also completes Q on iter 0
        const __hip_bfloat16* Kb = Fk + ((size_t)bb * S_TOTAL + t0) * KPAD;
        for (int g0 = wave * 64; g0 < GQ; g0 += 256) {
            int g = g0 + lane;
            glds16(Kb + (size_t)(g / GR) * KPAD + (g % GR) * 8, (char*)Ks + g0 * 16);
        }
        __syncthreads();

        f32x4 acc[4][4];
#pragma unroll
        for (int i = 0; i < 4; ++i)
#pragma unroll
            for (int j = 0; j < 4; ++j) acc[i][j] = (f32x4){0.f, 0.f, 0.f, 0.f};

#pragma unroll
        for (int ks = 0; ks < KPAD; ks += 32) {
            bf16x8 af[4], bfr[4];
#pragma unroll
            for (int i = 0; i < 4; ++i)
                af[i] = *(const bf16x8*)(Qs + (wm * 64 + i * 16 + l15) * KPAD + ks + quad * 8);
#pragma unroll
            for (int j = 0; j < 4; ++j)
                bfr[j] = *(const bf16x8*)(Ks + (wn * 64 + j * 16 + l15) * KPAD + ks + quad * 8);
#pragma unroll
            for (int i = 0; i < 4; ++i)
#pragma unroll
                for (int j = 0; j < 4; ++j)
                    acc[i][j] = __builtin_amdgcn_mfma_f32_16x16x32_bf16(
                        af[i], bfr[j], acc[i][j], 0, 0, 0);
        }

        // online softmax (base-2 domain; raw-score max, scale folded into fma)
#pragma unroll
        for (int i = 0; i < 4; ++i)
#pragma unroll
            for (int r = 0; r < 4; ++r) {
                int idx = i * 4 + r;
                float v0 = acc[i][0][r], v1 = acc[i][1][r];
                float v2 = acc[i][2][r], v3 = acc[i][3][r];
                float mx = fmaxf(fmaxf(v0, v1), fmaxf(v2, v3));
                float mn = fmaxf(m[idx], mx);
                float ms = mn * s2;
                float lv = l[idx] * exp2f(fmaf(m[idx], s2, -ms));
                lv += exp2f(fmaf(v0, s2, -ms)) + exp2f(fmaf(v1, s2, -ms));
                lv += exp2f(fmaf(v2, s2, -ms)) + exp2f(fmaf(v3, s2, -ms));
                m[idx] = mn; l[idx] = lv;
            }
    }

    // merge across the 16 col-lanes (lane bits 0..3)
#pragma unroll
    for (int off = 1; off < 16; off <<= 1)
#pragma unroll
        for (int i = 0; i < 16; ++i) {
            float mo = __shfl_xor(m[i], off);
            float lo = __shfl_xor(l[i], off);
            float mn = fmaxf(m[i], mo);
            l[i] = l[i] * exp2f((m[i] - mn) * s2) + lo * exp2f((mo - mn) * s2);
            m[i] = mn;
        }
    if (l15 == 0) {
        size_t base = (size_t)((bb * NSLICE + slice) * 2 + wn) * S_TOTAL;
#pragma unroll
        for (int i = 0; i < 4; ++i)
#pragma unroll
            for (int r = 0; r < 4; ++r) {
                int row = r0 + wm * 64 + i * 16 + quad * 4 + r;
                partial[base + row] = make_float2(m[i * 4 + r], l[i * 4 + r]);
            }
    }
}

// ---------------- merge 8 partials + pos diagonal -> loss
__global__ __launch_bounds__(256) void nce_reduce(
    const __hip_bfloat16* __restrict__ Fq, const __hip_bfloat16* __restrict__ Fk,
    const float2* __restrict__ partial, float* __restrict__ out,
    int KPAD, float s2, float inv_tau)
{
    __shared__ float red[4];
    const int tid = threadIdx.x;
    const int g = blockIdx.x * 256 + tid;
    const int bb = g >> 12, s = g & 4095;

    float M = -1e30f, L = 0.f;
    for (int p = 0; p < NSLICE * 2; ++p) {
        float2 pr = partial[(size_t)(bb * NSLICE * 2 + p) * S_TOTAL + s];
        float mn = fmaxf(M, pr.x);
        L = L * exp2f((M - mn) * s2) + pr.y * exp2f((pr.x - mn) * s2);
        M = mn;
    }
    const __hip_bfloat16* q = Fq + (size_t)g * KPAD;
    const __hip_bfloat16* k = Fk + (size_t)g * KPAD;
    float pos = 0.f;
    for (int c = 0; c < KPAD; ++c)
        pos += __bfloat162float(q[c]) * __bfloat162float(k[c]);
    float v = 0.6931471805599453f * (M * s2 + log2f(L)) - pos * inv_tau;
#pragma unroll
    for (int off = 1; off < 64; off <<= 1) v += __shfl_xor(v, off);
    if ((tid & 63) == 0) red[tid >> 6] = v;
    __syncthreads();
    if (tid == 0)
        atomicAdd(out, (red[0] + red[1] + red[2] + red[3]) * (1.0f / (float)M_TOTAL));
}

// ---------------- GEMM dispatch
static void launch_gemm(const __hip_bfloat16* X, const __hip_bfloat16* W,
                        const float* bias, __hip_bfloat16* Y,
                        int N, int K, int ldY, int relu, hipStream_t st)
{
    if (N >= 256)
        gemm_mfma<128><<<dim3(N / 128, 128), 256, 0, st>>>(X, W, bias, Y, K, ldY, relu);
    else if (N == 128)
        gemm_mfma<64><<<dim3(2, 128), 256, 0, st>>>(X, W, bias, Y, K, ldY, relu);
    else if (N == 64)
        gemm_mfma<64><<<dim3(1, 128), 256, 0, st>>>(X, W, bias, Y, K, ldY, relu);
    else if (N == 32)
        gemm_mfma<32><<<dim3(1, 128), 256, 0, st>>>(X, W, bias, Y, K, ldY, relu);
    else
        gemm_mfma<16><<<dim3(1, 128), 256, 0, st>>>(X, W, bias, Y, K, ldY, relu);
}

// ---------------- orchestration
extern "C" void kernel_launch(void* const* d_in, const int* in_sizes, int n_in,
                              void* d_out, int out_size, void* d_ws, size_t ws_size,
                              hipStream_t stream)
{
    (void)in_sizes; (void)n_in; (void)out_size; (void)ws_size;
    hipMemsetAsync(d_out, 0, sizeof(float), stream);

    static const int Cs[4]  = {64, 128, 256, 512};
    static const int HWs[4] = {256 * 256, 128 * 128, 64 * 64, 32 * 32};
    const float s2 = 144.26950408889634f;   // (1/tau) * log2(e)

    // workspace carve
    char* p = (char*)d_ws;
    __hip_bfloat16* Xb = (__hip_bfloat16*)p; p += (size_t)M_TOTAL * 512 * 2;
    __hip_bfloat16* Yb = (__hip_bfloat16*)p; p += (size_t)M_TOTAL * 512 * 2;
    __hip_bfloat16* Fq = (__hip_bfloat16*)p; p += (size_t)M_TOTAL * 128 * 2;
    __hip_bfloat16* Fk = (__hip_bfloat16*)p; p += (size_t)M_TOTAL * 128 * 2;
    float2* partial = (float2*)p;            p += (size_t)B_TOTAL * NSLICE * 2 * S_TOTAL * 8;
    __hip_bfloat16* wb = (__hip_bfloat16*)p;

    // weight conversion table
    WArgs wa;
    size_t off = 0;
    for (int i = 0; i < 4; ++i)
        for (int j = 0; j < 3; ++j) {
            int N = (j == 2) ? Cs[i] / 4 : Cs[i];
            int K = Cs[i];
            wa.s[i * 3 + j] = (const float*)d_in[i * 10 + 4 + j * 2];
            wa.d[i * 3 + j] = wb + off;
            wa.n[i * 3 + j] = N * K;
            off += (size_t)N * K;
        }
    convert_w<<<dim3(64, 12), 256, 0, stream>>>(wa);

    for (int i = 0; i < 4; ++i) {
        const int C = Cs[i], HW = HWs[i], Cout = C / 4;
        const int Kpad = (Cout < 32) ? 32 : Cout;
        const float* fq  = (const float*)d_in[i * 10 + 0];
        const float* fk  = (const float*)d_in[i * 10 + 1];
        const int*   cid = (const int*)  d_in[i * 10 + 2];
        const int*   nid = (const int*)  d_in[i * 10 + 3];
        const float* b0  = (const float*)d_in[i * 10 + 5];
        const float* b1  = (const float*)d_in[i * 10 + 7];
        const float* b2  = (const float*)d_in[i * 10 + 9];
        const __hip_bfloat16* w0b = wa.d[i * 3 + 0];
        const __hip_bfloat16* w1b = wa.d[i * 3 + 1];
        const __hip_bfloat16* w2b = wa.d[i * 3 + 2];

        if (Kpad > Cout) {   // zero pad columns (layer 0 only)
            hipMemsetAsync(Fq, 0, (size_t)M_TOTAL * Kpad * 2, stream);
            hipMemsetAsync(Fk, 0, (size_t)M_TOTAL * Kpad * 2, stream);
        }

        for (int qk = 0; qk < 2; ++qk) {
            const float* feat = qk ? fk : fq;
            __hip_bfloat16* F = qk ? Fk : Fq;
            gather_diff<<<dim3(S_TOTAL, B_TOTAL), 64, 0, stream>>>(
                feat, cid, nid, Xb, C, HW);
            launch_gemm(Xb, w0b, b0, Yb, C, C, C, 1, stream);
            launch_gemm(Yb, w1b, b1, Xb, C, C, C, 1, stream);
            launch_gemm(Xb, w2b, b2, F, Cout, C, Kpad, 0, stream);
        }

        dim3 ngrid(S_TOTAL / 128, NSLICE, B_TOTAL);
        if (Kpad == 32)
            nce_mfma<32><<<ngrid, 256, 0, stream>>>(Fq, Fk, partial, s2);
        else if (Kpad == 64)
            nce_mfma<64><<<ngrid, 256, 0, stream>>>(Fq, Fk, partial, s2);
        else
            nce_mfma<128><<<ngrid, 256, 0, stream>>>(Fq, Fk, partial, s2);

        nce_reduce<<<dim3(M_TOTAL / 256), 256, 0, stream>>>(
            Fq, Fk, partial, (float*)d_out, Kpad, s2, 100.0f);
    }
}